// Round 1
// baseline (275.496 us; speedup 1.0000x reference)
//
#include <hip/hip_runtime.h>

// BCE with per-class weights, reduced to a scalar.
// pred,true: (B=2, C=16, D=64, H=128, W=128) fp32; weight: (16,) fp32.
// final = sum_e w[c(e)] * bce_e / (B*D*H*W * sum(w))
//
// R5 (93.7 us kernel): one float4-pair per thread, 32768 blocks. Counter
// arithmetic: 439 cy per wave for 2 KB payload = 4.6 B/cy/CU vs ~10
// achievable -> wave-lifecycle-bound (6-deep shfl tail + barrier + WG
// launch per 32 B/thread), NOT bandwidth-bound.
// R6: amortize the tail 8x. Each thread loads 8 float4-pairs as ONE
// independent 16-load cluster (compiler emits counted vmcnt, compute of
// pair k overlaps in-flight loads), then one shuffle tail per 2048
// float4s instead of per 256. 4096 blocks.

static constexpr int kTotal = 2 * 16 * 64 * 128 * 128;  // 33,554,432
static constexpr int kN4 = kTotal / 4;                  // 8,388,608 float4s
static constexpr int kPairs = 8;                        // float4-pairs per thread
static constexpr int kBlockF4 = 256 * kPairs;           // 2048 float4s per block
static constexpr int kBlocks = kN4 / kBlockF4;          // 4096 blocks
static constexpr float kPerClassN = 2097152.0f;         // B*D*H*W = 2^21

__device__ __forceinline__ float bce4(const float4 p, const float4 t) {
  float a, lp, l1;
  lp = fmaxf(__logf(p.x), -100.0f);
  l1 = fmaxf(__logf(1.0f - p.x), -100.0f);
  a = l1 + t.x * (lp - l1);
  lp = fmaxf(__logf(p.y), -100.0f);
  l1 = fmaxf(__logf(1.0f - p.y), -100.0f);
  a += l1 + t.y * (lp - l1);
  lp = fmaxf(__logf(p.z), -100.0f);
  l1 = fmaxf(__logf(1.0f - p.z), -100.0f);
  a += l1 + t.z * (lp - l1);
  lp = fmaxf(__logf(p.w), -100.0f);
  l1 = fmaxf(__logf(1.0f - p.w), -100.0f);
  a += l1 + t.w * (lp - l1);
  return a;
}

__global__ __launch_bounds__(256) void bce_reduce_kernel(
    const float4* __restrict__ pred, const float4* __restrict__ tru,
    const float* __restrict__ weight, float* __restrict__ partials) {
  const int t = (int)threadIdx.x;
  const int base = blockIdx.x * kBlockF4 + t;
  // 2048 float4s/block; class column = 2^18 float4s = 128 blocks exactly.
  const float w = weight[(blockIdx.x >> 7) & 15];

  // One cluster of 16 independent loads, all in flight before any use.
  const float4 p0 = pred[base + 0 * 256];
  const float4 q0 = tru[base + 0 * 256];
  const float4 p1 = pred[base + 1 * 256];
  const float4 q1 = tru[base + 1 * 256];
  const float4 p2 = pred[base + 2 * 256];
  const float4 q2 = tru[base + 2 * 256];
  const float4 p3 = pred[base + 3 * 256];
  const float4 q3 = tru[base + 3 * 256];
  const float4 p4 = pred[base + 4 * 256];
  const float4 q4 = tru[base + 4 * 256];
  const float4 p5 = pred[base + 5 * 256];
  const float4 q5 = tru[base + 5 * 256];
  const float4 p6 = pred[base + 6 * 256];
  const float4 q6 = tru[base + 6 * 256];
  const float4 p7 = pred[base + 7 * 256];
  const float4 q7 = tru[base + 7 * 256];

  float acc = bce4(p0, q0);
  acc += bce4(p1, q1);
  acc += bce4(p2, q2);
  acc += bce4(p3, q3);
  acc += bce4(p4, q4);
  acc += bce4(p5, q5);
  acc += bce4(p6, q6);
  acc += bce4(p7, q7);

  // wave(64) shuffle reduction
  #pragma unroll
  for (int off = 32; off > 0; off >>= 1) acc += __shfl_down(acc, off, 64);

  __shared__ float smem[4];  // 256 threads = 4 waves
  const int lane = t & 63;
  const int wv = t >> 6;
  if (lane == 0) smem[wv] = acc;
  __syncthreads();
  if (t == 0) {
    const float blocksum = smem[0] + smem[1] + smem[2] + smem[3];
    partials[blockIdx.x] = -w * blocksum;  // plain store, no atomic
  }
}

__global__ __launch_bounds__(256) void bce_final_kernel(
    const float* __restrict__ weight, const float* __restrict__ partials,
    float* __restrict__ out) {
  // 4096 partials, 256 threads -> 16 each
  float acc = 0.0f;
  #pragma unroll
  for (int k = 0; k < 16; ++k) acc += partials[k * 256 + (int)threadIdx.x];

  #pragma unroll
  for (int off = 32; off > 0; off >>= 1) acc += __shfl_down(acc, off, 64);

  __shared__ float smem[4];
  const int lane = threadIdx.x & 63;
  const int wv = threadIdx.x >> 6;
  if (lane == 0) smem[wv] = acc;
  __syncthreads();
  if (threadIdx.x == 0) {
    float sw = 0.0f;
    #pragma unroll
    for (int c = 0; c < 16; ++c) sw += weight[c];
    out[0] = (smem[0] + smem[1] + smem[2] + smem[3]) / (kPerClassN * sw);
  }
}

extern "C" void kernel_launch(void* const* d_in, const int* in_sizes, int n_in,
                              void* d_out, int out_size, void* d_ws, size_t ws_size,
                              hipStream_t stream) {
  const float4* pred = (const float4*)d_in[0];
  const float4* tru = (const float4*)d_in[1];
  const float* weight = (const float*)d_in[2];
  float* out = (float*)d_out;
  float* partials = (float*)d_ws;  // 4096 floats = 16 KB of scratch (ws)

  bce_reduce_kernel<<<kBlocks, 256, 0, stream>>>(pred, tru, weight, partials);
  bce_final_kernel<<<1, 256, 0, stream>>>(weight, partials, out);
}

// Round 2
// 271.341 us; speedup vs baseline: 1.0153x; 1.0153x over previous
//
#include <hip/hip_runtime.h>

// BCE with per-class weights, reduced to a scalar.
// pred,true: (B=2, C=16, D=64, H=128, W=128) fp32; weight: (16,) fp32.
// final = sum_e w[c(e)] * bce_e / (B*D*H*W * sum(w))
//
// R7: REVERT to R5 streaming structure (proven 93.7 us).
// Evidence across R0-R6 (7 structures, 93.4-107 us): effective delivered
// BW is pinned at ~2.7-2.9 TB/s combined (FETCH_SIZE=134 MB: `true` is
// L3-resident from harness restore, `pred` streams from HBM at 1.35 TB/s).
// The harness's own restore phase (~173 us for ~478 MB r+w) runs at the
// SAME ~2.8 TB/s -> environmental streaming ceiling, not kernel structure.
// R6's 8-deep per-thread clusters (occupancy 52-57%) lost 6% vs R5's
// max-block streaming. Revert; widen final kernel to 1024 threads.

static constexpr int kTotal = 2 * 16 * 64 * 128 * 128;  // 33,554,432
static constexpr int kN4 = kTotal / 4;                  // 8,388,608 float4s
static constexpr int kBlocks = kN4 / 256;               // 32768 blocks
static constexpr float kPerClassN = 2097152.0f;         // B*D*H*W = 2^21

__global__ __launch_bounds__(256) void bce_reduce_kernel(
    const float4* __restrict__ pred, const float4* __restrict__ tru,
    const float* __restrict__ weight, float* __restrict__ partials) {
  const int i = blockIdx.x * 256 + (int)threadIdx.x;
  // class = (float4_index >> 18) & 15 = (blockIdx.x >> 10) & 15 (block-uniform)
  const float w = weight[(blockIdx.x >> 10) & 15];

  const float4 p = pred[i];
  const float4 t = tru[i];

  float acc = 0.0f;  // t*lp + (1-t)*l1 (un-negated, un-weighted)
  {
    const float lp = fmaxf(__logf(p.x), -100.0f);
    const float l1 = fmaxf(__logf(1.0f - p.x), -100.0f);
    acc += l1 + t.x * (lp - l1);
  }
  {
    const float lp = fmaxf(__logf(p.y), -100.0f);
    const float l1 = fmaxf(__logf(1.0f - p.y), -100.0f);
    acc += l1 + t.y * (lp - l1);
  }
  {
    const float lp = fmaxf(__logf(p.z), -100.0f);
    const float l1 = fmaxf(__logf(1.0f - p.z), -100.0f);
    acc += l1 + t.z * (lp - l1);
  }
  {
    const float lp = fmaxf(__logf(p.w), -100.0f);
    const float l1 = fmaxf(__logf(1.0f - p.w), -100.0f);
    acc += l1 + t.w * (lp - l1);
  }

  // wave(64) shuffle reduction
  #pragma unroll
  for (int off = 32; off > 0; off >>= 1) acc += __shfl_down(acc, off, 64);

  __shared__ float smem[4];  // 256 threads = 4 waves
  const int lane = threadIdx.x & 63;
  const int wv = threadIdx.x >> 6;
  if (lane == 0) smem[wv] = acc;
  __syncthreads();
  if (threadIdx.x == 0) {
    const float blocksum = smem[0] + smem[1] + smem[2] + smem[3];
    partials[blockIdx.x] = -w * blocksum;  // plain store, no atomic
  }
}

__global__ __launch_bounds__(1024) void bce_final_kernel(
    const float* __restrict__ weight, const float* __restrict__ partials,
    float* __restrict__ out) {
  // 32768 partials, 1024 threads -> 32 each (independent loads, L2/L3-hot)
  const int t = (int)threadIdx.x;
  float acc = 0.0f;
  #pragma unroll 8
  for (int k = 0; k < 32; ++k) acc += partials[k * 1024 + t];

  #pragma unroll
  for (int off = 32; off > 0; off >>= 1) acc += __shfl_down(acc, off, 64);

  __shared__ float smem[16];  // 1024 threads = 16 waves
  const int lane = t & 63;
  const int wv = t >> 6;
  if (lane == 0) smem[wv] = acc;
  __syncthreads();
  if (t == 0) {
    float s = 0.0f;
    #pragma unroll
    for (int v = 0; v < 16; ++v) s += smem[v];
    float sw = 0.0f;
    #pragma unroll
    for (int c = 0; c < 16; ++c) sw += weight[c];
    out[0] = s / (kPerClassN * sw);
  }
}

extern "C" void kernel_launch(void* const* d_in, const int* in_sizes, int n_in,
                              void* d_out, int out_size, void* d_ws, size_t ws_size,
                              hipStream_t stream) {
  const float4* pred = (const float4*)d_in[0];
  const float4* tru = (const float4*)d_in[1];
  const float* weight = (const float*)d_in[2];
  float* out = (float*)d_out;
  float* partials = (float*)d_ws;  // 32768 floats = 128 KB of scratch (ws)

  bce_reduce_kernel<<<kBlocks, 256, 0, stream>>>(pred, tru, weight, partials);
  bce_final_kernel<<<1, 1024, 0, stream>>>(weight, partials, out);
}

// Round 3
// 270.730 us; speedup vs baseline: 1.0176x; 1.0023x over previous
//
#include <hip/hip_runtime.h>

// BCE with per-class weights, reduced to a scalar.
// pred,true: (B=2, C=16, D=64, H=128, W=128) fp32; weight: (16,) fp32.
// final = sum_e w[c(e)] * bce_e / (B*D*H*W * sum(w))
//
// R8: REVERSE block sweep. Evidence: FETCH_SIZE = 131091 KB == pred's
// exact 131072 KB every rep -> `true` 100% L3-hit, `pred` 100% HBM-miss.
// Post-restore L3 should hold true (134MB) + pred's tail (~122MB); the
// forward sweep's 12MB of head misses LRU-evict pred's tail just ahead
// of the read cursor (cascade -> full miss). Streams are consumed in
// lockstep (each wave needs p AND t), so pred@HBM=1.44 TB/s paces both.
// Reverse sweep consumes the resident tail FIRST: misses only ~12MB head.
// Prediction: FETCH collapses to <~25e3 KB; if HBM-stream-bound, reduce
// 94 -> 50-70 us; if flat with collapsed FETCH, the ~2.9 TB/s aggregate
// delivery cap is proven -> roofline.

static constexpr int kTotal = 2 * 16 * 64 * 128 * 128;  // 33,554,432
static constexpr int kN4 = kTotal / 4;                  // 8,388,608 float4s
static constexpr int kBlocks = kN4 / 256;               // 32768 blocks
static constexpr float kPerClassN = 2097152.0f;         // B*D*H*W = 2^21

__global__ __launch_bounds__(256) void bce_reduce_kernel(
    const float4* __restrict__ pred, const float4* __restrict__ tru,
    const float* __restrict__ weight, float* __restrict__ partials) {
  // Reverse sweep: first-launched blocks read the (L3-resident) tail.
  const int rb = kBlocks - 1 - (int)blockIdx.x;
  const int i = rb * 256 + (int)threadIdx.x;
  // class = (float4_index >> 18) & 15 = (rb >> 10) & 15 (block-uniform)
  const float w = weight[(rb >> 10) & 15];

  const float4 p = pred[i];
  const float4 t = tru[i];

  float acc = 0.0f;  // t*lp + (1-t)*l1 (un-negated, un-weighted)
  {
    const float lp = fmaxf(__logf(p.x), -100.0f);
    const float l1 = fmaxf(__logf(1.0f - p.x), -100.0f);
    acc += l1 + t.x * (lp - l1);
  }
  {
    const float lp = fmaxf(__logf(p.y), -100.0f);
    const float l1 = fmaxf(__logf(1.0f - p.y), -100.0f);
    acc += l1 + t.y * (lp - l1);
  }
  {
    const float lp = fmaxf(__logf(p.z), -100.0f);
    const float l1 = fmaxf(__logf(1.0f - p.z), -100.0f);
    acc += l1 + t.z * (lp - l1);
  }
  {
    const float lp = fmaxf(__logf(p.w), -100.0f);
    const float l1 = fmaxf(__logf(1.0f - p.w), -100.0f);
    acc += l1 + t.w * (lp - l1);
  }

  // wave(64) shuffle reduction
  #pragma unroll
  for (int off = 32; off > 0; off >>= 1) acc += __shfl_down(acc, off, 64);

  __shared__ float smem[4];  // 256 threads = 4 waves
  const int lane = threadIdx.x & 63;
  const int wv = threadIdx.x >> 6;
  if (lane == 0) smem[wv] = acc;
  __syncthreads();
  if (threadIdx.x == 0) {
    const float blocksum = smem[0] + smem[1] + smem[2] + smem[3];
    partials[blockIdx.x] = -w * blocksum;  // plain store, no atomic
  }
}

__global__ __launch_bounds__(1024) void bce_final_kernel(
    const float* __restrict__ weight, const float* __restrict__ partials,
    float* __restrict__ out) {
  // 32768 partials, 1024 threads -> 32 each (independent loads, L2/L3-hot)
  const int t = (int)threadIdx.x;
  float acc = 0.0f;
  #pragma unroll 8
  for (int k = 0; k < 32; ++k) acc += partials[k * 1024 + t];

  #pragma unroll
  for (int off = 32; off > 0; off >>= 1) acc += __shfl_down(acc, off, 64);

  __shared__ float smem[16];  // 1024 threads = 16 waves
  const int lane = t & 63;
  const int wv = t >> 6;
  if (lane == 0) smem[wv] = acc;
  __syncthreads();
  if (t == 0) {
    float s = 0.0f;
    #pragma unroll
    for (int v = 0; v < 16; ++v) s += smem[v];
    float sw = 0.0f;
    #pragma unroll
    for (int c = 0; c < 16; ++c) sw += weight[c];
    out[0] = s / (kPerClassN * sw);
  }
}

extern "C" void kernel_launch(void* const* d_in, const int* in_sizes, int n_in,
                              void* d_out, int out_size, void* d_ws, size_t ws_size,
                              hipStream_t stream) {
  const float4* pred = (const float4*)d_in[0];
  const float4* tru = (const float4*)d_in[1];
  const float* weight = (const float*)d_in[2];
  float* out = (float*)d_out;
  float* partials = (float*)d_ws;  // 32768 floats = 128 KB of scratch (ws)

  bce_reduce_kernel<<<kBlocks, 256, 0, stream>>>(pred, tru, weight, partials);
  bce_final_kernel<<<1, 1024, 0, stream>>>(weight, partials, out);
}